// Round 1
// baseline (489.728 us; speedup 1.0000x reference)
//
#include <hip/hip_runtime.h>

typedef unsigned short u16;
typedef short bf16x8 __attribute__((ext_vector_type(8)));
typedef float f32x4 __attribute__((ext_vector_type(4)));
typedef unsigned short u16x8 __attribute__((ext_vector_type(8)));

#define DEVFN static __device__ __forceinline__

DEVFN u16 f2b(float f) {
    unsigned int u = __builtin_bit_cast(unsigned int, f);
    u += 0x7FFFu + ((u >> 16) & 1u);
    return (u16)(u >> 16);
}
DEVFN float b2f(u16 h) {
    unsigned int u = ((unsigned int)h) << 16;
    return __builtin_bit_cast(float, u);
}

// ---------------------------------------------------------------- prep ----
__global__ void k_prep(const float* __restrict__ qkvw, const float* __restrict__ pjw,
                       u16* __restrict__ qkvwb, u16* __restrict__ pjwb) {
    int id = blockIdx.x * 256 + threadIdx.x;
    if (id < 196608) qkvwb[id] = f2b(qkvw[id]);
    if (id < 65536)  pjwb[id]  = f2b(pjw[id]);
}

__global__ void k_cpb(const float* __restrict__ w1, const float* __restrict__ b1,
                      const float* __restrict__ w2, float* __restrict__ bt) {
    int p = threadIdx.x;
    if (p >= 225) return;
    int d0 = p / 15, d1 = p % 15;
    float v0 = (float)(d0 - 7) * (8.0f / 7.0f);
    float v1 = (float)(d1 - 7) * (8.0f / 7.0f);
    float t0 = copysignf(log2f(fabsf(v0) + 1.0f) * (1.0f / 3.0f), v0);
    float t1 = copysignf(log2f(fabsf(v1) + 1.0f) * (1.0f / 3.0f), v1);
    float s[8] = {0.f, 0.f, 0.f, 0.f, 0.f, 0.f, 0.f, 0.f};
    for (int d = 0; d < 256; ++d) {
        float h = t0 * w1[2 * d] + t1 * w1[2 * d + 1] + b1[d];
        h = fmaxf(h, 0.0f);
        #pragma unroll
        for (int hh = 0; hh < 8; ++hh) s[hh] += h * w2[hh * 256 + d];
    }
    #pragma unroll
    for (int hh = 0; hh < 8; ++hh) bt[p * 8 + hh] = s[hh];
}

__global__ void k_bias(const float* __restrict__ bt, float* __restrict__ bias) {
    int id = blockIdx.x * 256 + threadIdx.x;  // 4096 = 64*64
    int i = id >> 6, j = id & 63;
    int d0 = (i >> 3) - (j >> 3) + 7;
    int d1 = (i & 7) - (j & 7) + 7;
    int p = d0 * 15 + d1;
    #pragma unroll
    for (int h = 0; h < 8; ++h)
        bias[h * 4096 + id] = 16.0f / (1.0f + expf(-bt[p * 8 + h]));
}

// ---------------------------------------------------------------- attn ----
// one block = one 8x8 window (512 thr, 8 waves); wave w = head w.
// LDS: Xs [64][256] bf16 swizzled + per-wave scratch (q,k 64x32 / v_t 32x64 / P 64x64)
__global__ __launch_bounds__(512, 2) void k_attn(
    const float* __restrict__ x, const u16* __restrict__ qkvw,
    const float* __restrict__ qkvb, const float* __restrict__ lsc,
    const float* __restrict__ bias, u16* __restrict__ wv_g, u16* __restrict__ wout_g) {
    __shared__ __align__(16) u16 Xs[64 * 256];
    __shared__ __align__(16) u16 scr[8 * 6144];

    const int win = blockIdx.x;
    const int b = win >> 8;
    const int h0 = ((win >> 4) & 15) * 8;
    const int w0 = (win & 15) * 8;
    const int tid = threadIdx.x;
    const int wave = tid >> 6;
    const int l = tid & 63;
    const int col = l & 15;
    const int quad = l >> 4;

    // stage x window -> LDS bf16, rows of 256 ch, 16B-chunk XOR swizzle
    for (int p = tid; p < 2048; p += 512) {
        const int ch = p >> 3, r = p & 7;
        const float* src = x + (((size_t)b * 256 + ch) * 128 + (h0 + r)) * 128 + w0;
        const float4 a0 = *(const float4*)src;
        const float4 a1 = *(const float4*)(src + 4);
        float vv[8] = {a0.x, a0.y, a0.z, a0.w, a1.x, a1.y, a1.z, a1.w};
        const int t0 = r * 8;
        #pragma unroll
        for (int c = 0; c < 8; ++c) {
            const int t = t0 + c;
            Xs[t * 256 + ((((ch >> 3) ^ (t & 7)) << 3) | (ch & 7))] = f2b(vv[c]);
        }
    }
    __syncthreads();

    const int h = wave;
    const f32x4 zero4 = {0.f, 0.f, 0.f, 0.f};
    f32x4 acc[4][6];
    #pragma unroll
    for (int mt = 0; mt < 4; ++mt)
        #pragma unroll
        for (int nt = 0; nt < 6; ++nt) acc[mt][nt] = zero4;

    // QKV GEMM: M=64 tok, N=96 (q|k|v of this head), K=256
    for (int kk = 0; kk < 8; ++kk) {
        const int cb = kk * 32 + quad * 8;
        bf16x8 af[4];
        #pragma unroll
        for (int mt = 0; mt < 4; ++mt) {
            const int t = mt * 16 + col;
            af[mt] = *(const bf16x8*)&Xs[t * 256 + (((cb >> 3) ^ (t & 7)) << 3)];
        }
        #pragma unroll
        for (int nt = 0; nt < 6; ++nt) {
            const int o = h * 96 + (nt >> 1) * 32 + (nt & 1) * 16 + col;
            const bf16x8 bw = *(const bf16x8*)&qkvw[(size_t)o * 256 + cb];
            #pragma unroll
            for (int mt = 0; mt < 4; ++mt)
                acc[mt][nt] = __builtin_amdgcn_mfma_f32_16x16x32_bf16(af[mt], bw, acc[mt][nt], 0, 0, 0);
        }
    }

    // epilogue: +bias, L2-normalize q,k; stash q,k,v^T,v-global
    float bq[6];
    #pragma unroll
    for (int nt = 0; nt < 6; ++nt)
        bq[nt] = qkvb[h * 96 + (nt >> 1) * 32 + (nt & 1) * 16 + col];
    const float ls = expf(fminf(lsc[h], 4.6051701859880914f));

    u16* const q_s = scr + wave * 6144;  // [64][32] swz(i&3)
    u16* const k_s = q_s + 2048;         // [64][32] swz(i&3)
    u16* const v_t = q_s + 4096;         // [32][64] swz(d&7)

    #pragma unroll
    for (int mt = 0; mt < 4; ++mt) {
        float q0[4], q1[4], k0[4], k1[4], v0[4], v1[4], sq[4], sk[4];
        #pragma unroll
        for (int r = 0; r < 4; ++r) {
            q0[r] = acc[mt][0][r] + bq[0]; q1[r] = acc[mt][1][r] + bq[1];
            k0[r] = acc[mt][2][r] + bq[2]; k1[r] = acc[mt][3][r] + bq[3];
            v0[r] = acc[mt][4][r] + bq[4]; v1[r] = acc[mt][5][r] + bq[5];
            sq[r] = q0[r] * q0[r] + q1[r] * q1[r];
            sk[r] = k0[r] * k0[r] + k1[r] * k1[r];
        }
        #pragma unroll
        for (int m = 1; m < 16; m <<= 1) {
            #pragma unroll
            for (int r = 0; r < 4; ++r) {
                sq[r] += __shfl_xor(sq[r], m, 64);
                sk[r] += __shfl_xor(sk[r], m, 64);
            }
        }
        #pragma unroll
        for (int r = 0; r < 4; ++r) {
            const int t = mt * 16 + quad * 4 + r;
            const float qi = 1.0f / fmaxf(sqrtf(sq[r]), 1e-12f);
            const float ki = 1.0f / fmaxf(sqrtf(sk[r]), 1e-12f);
            q_s[t * 32 + ((((col >> 3) ^ (t & 3)) << 3) | (col & 7))] = f2b(q0[r] * qi);
            q_s[t * 32 + (((((col + 16) >> 3) ^ (t & 3)) << 3) | (col & 7))] = f2b(q1[r] * qi);
            k_s[t * 32 + ((((col >> 3) ^ (t & 3)) << 3) | (col & 7))] = f2b(k0[r] * ki);
            k_s[t * 32 + (((((col + 16) >> 3) ^ (t & 3)) << 3) | (col & 7))] = f2b(k1[r] * ki);
            const u16 vb0 = f2b(v0[r]), vb1 = f2b(v1[r]);
            v_t[col * 64 + ((((t >> 3) ^ (col & 7)) << 3) | (t & 7))] = vb0;
            v_t[(col + 16) * 64 + ((((t >> 3) ^ ((col + 16) & 7)) << 3) | (t & 7))] = vb1;
            u16* wvp = wv_g + ((size_t)win * 64 + t) * 256 + h * 32;
            wvp[col] = vb0;
            wvp[col + 16] = vb1;
        }
    }
    __syncthreads();

    // S = (qn . kn^T)*ls + bias ; softmax rows
    f32x4 sacc[4][4];
    {
        const int kb = quad * 8;
        bf16x8 aq[4], bk[4];
        #pragma unroll
        for (int mt = 0; mt < 4; ++mt) {
            const int i = mt * 16 + col;
            const int sw = (((kb >> 3) ^ (i & 3)) << 3);
            aq[mt] = *(const bf16x8*)&q_s[i * 32 + sw];
            bk[mt] = *(const bf16x8*)&k_s[i * 32 + sw];
        }
        #pragma unroll
        for (int mt = 0; mt < 4; ++mt)
            #pragma unroll
            for (int nt = 0; nt < 4; ++nt)
                sacc[mt][nt] = __builtin_amdgcn_mfma_f32_16x16x32_bf16(aq[mt], bk[nt], zero4, 0, 0, 0);
    }
    const float* bh = bias + h * 4096;
    #pragma unroll
    for (int mt = 0; mt < 4; ++mt) {
        #pragma unroll
        for (int r = 0; r < 4; ++r) {
            const int i = mt * 16 + quad * 4 + r;
            float v[4];
            #pragma unroll
            for (int nt = 0; nt < 4; ++nt)
                v[nt] = sacc[mt][nt][r] * ls + bh[i * 64 + nt * 16 + col];
            float mx = fmaxf(fmaxf(v[0], v[1]), fmaxf(v[2], v[3]));
            #pragma unroll
            for (int m = 1; m < 16; m <<= 1) mx = fmaxf(mx, __shfl_xor(mx, m, 64));
            float s = 0.f;
            #pragma unroll
            for (int nt = 0; nt < 4; ++nt) { v[nt] = expf(v[nt] - mx); s += v[nt]; }
            #pragma unroll
            for (int m = 1; m < 16; m <<= 1) s += __shfl_xor(s, m, 64);
            const float inv = 1.0f / s;
            #pragma unroll
            for (int nt = 0; nt < 4; ++nt) sacc[mt][nt][r] = v[nt] * inv;
        }
    }
    // P -> LDS (aliases q_s+k_s), [64][64] swz(i&7)
    u16* const p_s = q_s;
    #pragma unroll
    for (int mt = 0; mt < 4; ++mt)
        #pragma unroll
        for (int r = 0; r < 4; ++r) {
            const int i = mt * 16 + quad * 4 + r;
            #pragma unroll
            for (int nt = 0; nt < 4; ++nt) {
                const int j = nt * 16 + col;
                p_s[i * 64 + ((((j >> 3) ^ (i & 7)) << 3) | (j & 7))] = f2b(sacc[mt][nt][r]);
            }
        }
    __syncthreads();

    // out = P @ V   (A=P [64][64], B via v_t [d][j])
    f32x4 oacc[4][2];
    #pragma unroll
    for (int mt = 0; mt < 4; ++mt)
        #pragma unroll
        for (int nt = 0; nt < 2; ++nt) oacc[mt][nt] = zero4;
    #pragma unroll
    for (int kk = 0; kk < 2; ++kk) {
        const int kb = kk * 32 + quad * 8;
        bf16x8 ap[4];
        #pragma unroll
        for (int mt = 0; mt < 4; ++mt) {
            const int i = mt * 16 + col;
            ap[mt] = *(const bf16x8*)&p_s[i * 64 + (((kb >> 3) ^ (i & 7)) << 3)];
        }
        bf16x8 bv[2];
        #pragma unroll
        for (int nt = 0; nt < 2; ++nt) {
            const int d = nt * 16 + col;
            bv[nt] = *(const bf16x8*)&v_t[d * 64 + (((kb >> 3) ^ (d & 7)) << 3)];
        }
        #pragma unroll
        for (int mt = 0; mt < 4; ++mt)
            #pragma unroll
            for (int nt = 0; nt < 2; ++nt)
                oacc[mt][nt] = __builtin_amdgcn_mfma_f32_16x16x32_bf16(ap[mt], bv[nt], oacc[mt][nt], 0, 0, 0);
    }
    #pragma unroll
    for (int mt = 0; mt < 4; ++mt)
        #pragma unroll
        for (int nt = 0; nt < 2; ++nt)
            #pragma unroll
            for (int r = 0; r < 4; ++r) {
                const int t = mt * 16 + quad * 4 + r;
                wout_g[((size_t)win * 64 + t) * 256 + h * 32 + nt * 16 + col] = f2b(oacc[mt][nt][r]);
            }
}

// ---------------------------------------------------------------- proj ----
// one block = one window; y = wout + dwconv3x3(wv) + pe_b  -> LDS; then proj GEMM
__global__ __launch_bounds__(256, 4) void k_proj(
    const u16* __restrict__ wout_g, const u16* __restrict__ wv_g,
    const float* __restrict__ pe_w, const float* __restrict__ pe_b,
    const u16* __restrict__ pjw, const float* __restrict__ pjb,
    float* __restrict__ out) {
    __shared__ __align__(16) u16 y_s[64 * 256];
    const int win = blockIdx.x;
    const int b = win >> 8;
    const int h0 = ((win >> 4) & 15) * 8;
    const int w0 = (win & 15) * 8;
    const int tid = threadIdx.x;
    const int cg = tid & 31, ch = cg * 8;
    const int psub = tid >> 5;

    float pw[9][8];
    #pragma unroll
    for (int j = 0; j < 8; ++j)
        #pragma unroll
        for (int k = 0; k < 9; ++k) pw[k][j] = pe_w[(ch + j) * 9 + k];
    float pb[8];
    #pragma unroll
    for (int j = 0; j < 8; ++j) pb[j] = pe_b[ch + j];

    for (int it = 0; it < 8; ++it) {
        const int p = it * 8 + psub;
        const int gh = h0 + (p >> 3), gw = w0 + (p & 7);
        float a[8];
        {
            const bf16x8 ov = *(const bf16x8*)&wout_g[((size_t)win * 64 + p) * 256 + ch];
            #pragma unroll
            for (int j = 0; j < 8; ++j) a[j] = b2f((u16)ov[j]) + pb[j];
        }
        #pragma unroll
        for (int dy = -1; dy <= 1; ++dy)
            #pragma unroll
            for (int dx = -1; dx <= 1; ++dx) {
                const int hh = gh + dy, ww2 = gw + dx;
                if (hh < 0 || hh >= 128 || ww2 < 0 || ww2 >= 128) continue;
                const int nwin = b * 256 + (hh >> 3) * 16 + (ww2 >> 3);
                const int ntk = (hh & 7) * 8 + (ww2 & 7);
                const bf16x8 vv = *(const bf16x8*)&wv_g[((size_t)nwin * 64 + ntk) * 256 + ch];
                const int k = (dy + 1) * 3 + (dx + 1);
                #pragma unroll
                for (int j = 0; j < 8; ++j) a[j] += b2f((u16)vv[j]) * pw[k][j];
            }
        u16x8 tmp;
        #pragma unroll
        for (int j = 0; j < 8; ++j) tmp[j] = f2b(a[j]);
        *(u16x8*)&y_s[p * 256 + (((ch >> 3) ^ (p & 7)) << 3)] = tmp;
    }
    __syncthreads();

    // out[o][p] = proj_w[o][:] . y[p][:]  (M=256 split over 4 waves, N=64, K=256)
    const int wave = tid >> 6, l = tid & 63;
    const int col = l & 15, quad = l >> 4;
    const f32x4 zero4 = {0.f, 0.f, 0.f, 0.f};
    f32x4 macc[4][4];
    #pragma unroll
    for (int mt = 0; mt < 4; ++mt)
        #pragma unroll
        for (int nt = 0; nt < 4; ++nt) macc[mt][nt] = zero4;
    const int ob = wave * 64;
    for (int kk = 0; kk < 8; ++kk) {
        const int cb = kk * 32 + quad * 8;
        bf16x8 aw[4], by[4];
        #pragma unroll
        for (int mt = 0; mt < 4; ++mt)
            aw[mt] = *(const bf16x8*)&pjw[(size_t)(ob + mt * 16 + col) * 256 + cb];
        #pragma unroll
        for (int nt = 0; nt < 4; ++nt) {
            const int p = nt * 16 + col;
            by[nt] = *(const bf16x8*)&y_s[p * 256 + (((cb >> 3) ^ (p & 7)) << 3)];
        }
        #pragma unroll
        for (int mt = 0; mt < 4; ++mt)
            #pragma unroll
            for (int nt = 0; nt < 4; ++nt)
                macc[mt][nt] = __builtin_amdgcn_mfma_f32_16x16x32_bf16(aw[mt], by[nt], macc[mt][nt], 0, 0, 0);
    }
    #pragma unroll
    for (int mt = 0; mt < 4; ++mt)
        #pragma unroll
        for (int r = 0; r < 4; ++r) {
            const int o = ob + mt * 16 + quad * 4 + r;
            const float pbv = pjb[o];
            #pragma unroll
            for (int nt = 0; nt < 4; ++nt) {
                const int p = nt * 16 + col;
                out[(((size_t)b * 256 + o) * 128 + h0 + (p >> 3)) * 128 + w0 + (p & 7)] =
                    macc[mt][nt][r] + pbv;
            }
        }
}

// -------------------------------------------------------------- launch ----
extern "C" void kernel_launch(void* const* d_in, const int* in_sizes, int n_in,
                              void* d_out, int out_size, void* d_ws, size_t ws_size,
                              hipStream_t stream) {
    const float* x    = (const float*)d_in[0];
    const float* qkvw = (const float*)d_in[1];
    const float* qkvb = (const float*)d_in[2];
    const float* pjw  = (const float*)d_in[3];
    const float* pjb  = (const float*)d_in[4];
    const float* pew  = (const float*)d_in[5];
    const float* peb  = (const float*)d_in[6];
    const float* lsc  = (const float*)d_in[7];
    const float* w1   = (const float*)d_in[8];
    const float* b1   = (const float*)d_in[9];
    const float* w2   = (const float*)d_in[10];

    char* ws = (char*)d_ws;
    u16* wv_b    = (u16*)(ws);                                   // 64 MiB
    u16* wout_b  = (u16*)(ws + (64ull << 20));                   // 64 MiB
    u16* qkvwb   = (u16*)(ws + (128ull << 20));                  // 384 KiB
    u16* pjwb    = (u16*)(ws + (128ull << 20) + 393216);         // 128 KiB
    float* bias  = (float*)(ws + (128ull << 20) + 393216 + 131072);   // 128 KiB
    float* bt    = (float*)(ws + (128ull << 20) + 393216 + 262144);   // 7.2 KiB

    hipLaunchKernelGGL(k_prep, dim3(768), dim3(256), 0, stream, qkvw, pjw, qkvwb, pjwb);
    hipLaunchKernelGGL(k_cpb,  dim3(1),   dim3(256), 0, stream, w1, b1, w2, bt);
    hipLaunchKernelGGL(k_bias, dim3(16),  dim3(256), 0, stream, bt, bias);
    hipLaunchKernelGGL(k_attn, dim3(2048), dim3(512), 0, stream,
                       x, qkvwb, qkvb, lsc, bias, wv_b, wout_b);
    hipLaunchKernelGGL(k_proj, dim3(2048), dim3(256), 0, stream,
                       wout_b, wv_b, pew, peb, pjwb, pjb, (float*)d_out);
}